// Round 10
// baseline (203.006 us; speedup 1.0000x reference)
//
#include <hip/hip_runtime.h>
#include <hip/hip_bf16.h>

typedef float f32x4 __attribute__((ext_vector_type(4)));
typedef __bf16 bf16x8 __attribute__((ext_vector_type(8)));
typedef __bf16 bf16x4 __attribute__((ext_vector_type(4)));
typedef short s16x4 __attribute__((ext_vector_type(4)));

constexpr int C = 256;
constexpr int N = 2304;           // 48*48 tokens per batch
constexpr int T = 2 * N;          // total tokens

#if __has_builtin(__builtin_amdgcn_exp2f)
#define EXP2F(x) __builtin_amdgcn_exp2f(x)
#else
#define EXP2F(x) exp2f(x)
#endif

__device__ __forceinline__ bf16x8 load_bf8(const __bf16* p) {
    return *reinterpret_cast<const bf16x8*>(p);
}

__device__ __forceinline__ f32x4 mfma32(bf16x8 a, bf16x8 b, f32x4 c) {
    return __builtin_amdgcn_mfma_f32_16x16x32_bf16(a, b, c, 0, 0, 0);
}

// K=16 MFMA: 4-element k-granules match the QK^T C/D output layout, so P feeds
// PV entirely in-register (no LDS redistribution). Verified correct R4-R9.
#if __has_builtin(__builtin_amdgcn_mfma_f32_16x16x16bf16_1k)
__device__ __forceinline__ f32x4 mfma16(bf16x4 a, bf16x4 b, f32x4 c) {
    return __builtin_amdgcn_mfma_f32_16x16x16bf16_1k(
        __builtin_bit_cast(s16x4, a), __builtin_bit_cast(s16x4, b), c, 0, 0, 0);
}
#else
__device__ __forceinline__ f32x4 mfma16(bf16x4 a, bf16x4 b, f32x4 c) {
    f32x4 d;
    asm volatile("v_mfma_f32_16x16x16_bf16 %0, %1, %2, %3"
                 : "=v"(d) : "v"(a), "v"(b), "v"(c));
    return d;
}
#endif

// async global->LDS, 16B per lane; dest = wave-uniform base + lane*16
__device__ __forceinline__ void gload_lds16(const __bf16* g, __bf16* l) {
    __builtin_amdgcn_global_load_lds(
        (const __attribute__((address_space(1))) void*)g,
        (__attribute__((address_space(3))) void*)l, 16, 0, 0);
}

#define VMCNT0() asm volatile("s_waitcnt vmcnt(0)" ::: "memory")
#define LGKM0()  asm volatile("s_waitcnt lgkmcnt(0)" ::: "memory")

// ---------------- kernel 0: convert Wq/Wk/Wv/Wo to bf16 ----------------
__global__ void wconv_kernel(const float* __restrict__ Wq, const float* __restrict__ Wk,
                             const float* __restrict__ Wv, const float* __restrict__ Wo,
                             __bf16* __restrict__ Wb) {
    const float* srcs[4] = {Wq, Wk, Wv, Wo};
    int m = blockIdx.x >> 6;
    int idx = (blockIdx.x & 63) * 256 + threadIdx.x;   // [0, 16384)
    float4 v = reinterpret_cast<const float4*>(srcs[m])[idx];
    bf16x4 o = { (__bf16)v.x, (__bf16)v.y, (__bf16)v.z, (__bf16)v.w };
    reinterpret_cast<bf16x4*>(Wb + m * 65536)[idx] = o;
}

// ---------------- kernel 1: gate + transpose (32-row tiles, 576 blocks) ----------------
__global__ void prep_kernel(const float* __restrict__ x, const float* __restrict__ u,
                            const float* __restrict__ Wg, const float* __restrict__ bg,
                            __bf16* __restrict__ xT, __bf16* __restrict__ gxT) {
    __shared__ float tile[32][65];
    int b = blockIdx.z, c0 = blockIdx.y * 32, n0 = blockIdx.x * 64;
    int t = threadIdx.x;
    const float* xp = x + (b * C + c0) * N + n0;
    #pragma unroll
    for (int r = 0; r < 8; ++r) {
        int cl = r * 4 + (t >> 6);
        int nl = t & 63;
        tile[cl][nl] = xp[cl * N + nl];
    }
    __syncthreads();
    int cq = (t & 7) * 4;
    #pragma unroll
    for (int it = 0; it < 2; ++it) {
        int nl = it * 32 + (t >> 3);
        float uv = u[b * N + n0 + nl];
        bf16x4 xo, go;
        #pragma unroll
        for (int j = 0; j < 4; ++j) {
            int c = c0 + cq + j;
            float xv = tile[cq + j][nl];
            float gate = 1.0f - (Wg[c] * uv + bg[c]);
            xo[j] = (__bf16)xv;
            go[j] = (__bf16)(xv * gate);
        }
        int tok = b * N + n0 + nl;
        *reinterpret_cast<bf16x4*>(xT + (long)tok * C + c0 + cq) = xo;
        *reinterpret_cast<bf16x4*>(gxT + (long)tok * C + c0 + cq) = go;
    }
}

// ---------------- kernel 2: QKV projections (bf16 MFMA) ----------------
// Q[bh][n][d], K[bh][m][d] (pre-scaled by SCALE*log2e*(1-u[m])), V[bh][d][n]
__global__ __launch_bounds__(256) void qkv_kernel(const __bf16* __restrict__ Wb,
    const __bf16* __restrict__ xT, const __bf16* __restrict__ gxT,
    const float* __restrict__ bq, const float* __restrict__ bk, const float* __restrict__ bv,
    const float* __restrict__ u,
    __bf16* __restrict__ Q, __bf16* __restrict__ K, __bf16* __restrict__ V) {
    int proj = blockIdx.z;            // 0=q,1=k,2=v
    int o0 = blockIdx.y * 64;
    int t0 = blockIdx.x * 32;
    int wave = threadIdx.x >> 6, lane = threadIdx.x & 63;
    int g = lane >> 4, r = lane & 15;
    int ow = o0 + wave * 16;
    const __bf16* W = Wb + proj * 65536;
    const __bf16* inp = (proj == 2) ? xT : gxT;
    f32x4 acc[2] = {};
    for (int k = 0; k < 8; ++k) {
        bf16x8 a = load_bf8(W + (ow + r) * C + k * 32 + g * 8);
        #pragma unroll
        for (int tb = 0; tb < 2; ++tb) {
            bf16x8 bfr = load_bf8(inp + (long)(t0 + tb * 16 + r) * C + k * 32 + g * 8);
            acc[tb] = mfma32(a, bfr, acc[tb]);
        }
    }
    const float* bias = (proj == 0) ? bq : (proj == 1) ? bk : bv;
    float bvw[4];
    #pragma unroll
    for (int i = 0; i < 4; ++i) bvw[i] = bias[ow + g * 4 + i];
    int h = ow >> 5, d0 = (ow & 31) + g * 4;
    const float SC = 0.17677669529663687f * 1.4426950408889634f;  // SCALE * log2(e)
    #pragma unroll
    for (int tb = 0; tb < 2; ++tb) {
        int t = t0 + tb * 16 + r;
        int b = t / N, n = t % N;
        if (proj == 2) {
            #pragma unroll
            for (int i = 0; i < 4; ++i)
                V[((long)(b * 8 + h) * 32 + d0 + i) * N + n] = (__bf16)(acc[tb][i] + bvw[i]);
        } else {
            bf16x4 outv;
            if (proj == 1) {
                float scale = SC * (1.0f - u[t]);
                #pragma unroll
                for (int i = 0; i < 4; ++i) outv[i] = (__bf16)((acc[tb][i] + bvw[i]) * scale);
            } else {
                #pragma unroll
                for (int i = 0; i < 4; ++i) outv[i] = (__bf16)(acc[tb][i] + bvw[i]);
            }
            __bf16* dst = (proj == 0) ? Q : K;
            *reinterpret_cast<bf16x4*>(dst + ((long)(b * 8 + h) * N + n) * 32 + d0) = outv;
        }
    }
}

// ---------------- kernel 3: flash attention (R9-identical; measurement round) ----------------
__global__ __launch_bounds__(256) void attn_kernel(const __bf16* __restrict__ Q,
    const __bf16* __restrict__ K, const __bf16* __restrict__ V,
    __bf16* __restrict__ aoT) {
    __shared__ __bf16 sK[2][2][2048];   // [pair][buf][64 keys x 32 d] linear
    __shared__ __bf16 sV[2][2][2048];   // [pair][buf][32 d x 64 m] chunk-swizzled
    int id = blockIdx.x;                // 1152 = 8 xcd * 144
    int xcd = id & 7, j = id >> 3;      // j in [0,144)
    int bh = xcd + 8 * (j / 72);
    int qblk = j % 72;
    int tid = threadIdx.x;
    int wave = tid >> 6, lane = tid & 63;
    int wp = wave & 1, pair = wave >> 1;
    int g = lane >> 4, r = lane & 15;
    int q0 = qblk * 32;
    const __bf16* Qg = Q + (long)bh * N * 32;
    const __bf16* Kg = K + (long)bh * N * 32 + (long)pair * 1152 * 32;
    const __bf16* Vg = V + (long)bh * 32 * N + pair * 1152;
    bf16x8 qf = load_bf8(Qg + (q0 + wp * 16 + r) * 32 + g * 8);   // B-frag Q^T
    long ksrc = (long)(wp * 64 + lane) * 8;
    int rr1 = wp * 8 + (lane >> 3);
    long vsrc0 = (long)rr1 * N + ((lane & 7) ^ ((rr1 >> 1) & 7)) * 8;
    int rr2 = 16 + rr1;
    long vsrc1 = (long)rr2 * N + ((lane & 7) ^ ((rr2 >> 1) & 7)) * 8;
    __bf16* kb0 = &sK[pair][0][0];
    __bf16* kb1 = &sK[pair][1][0];
    __bf16* vb0 = &sV[pair][0][0];
    __bf16* vb1 = &sV[pair][1][0];
    auto STAGE = [&](long m0, __bf16* kd, __bf16* vd) {
        gload_lds16(Kg + m0 * 32 + ksrc,        kd + wp * 512);
        gload_lds16(Kg + m0 * 32 + 1024 + ksrc, kd + 1024 + wp * 512);
        gload_lds16(Vg + vsrc0 + m0,            vd + wp * 512);
        gload_lds16(Vg + vsrc1 + m0,            vd + 1024 + wp * 512);
    };
    bf16x4 onesv;
    #pragma unroll
    for (int i = 0; i < 4; ++i) onesv[i] = (__bf16)1.0f;
    f32x4 oa0 = {}, oa1 = {}, oal = {};
    int k2r = (r >> 1) & 7;          // V read swizzle key
    STAGE(0, kb0, vb0);
    for (int t = 0; t < 18; ++t) {
        LGKM0();                     // my reads of tile t-1 done (WAR)
        VMCNT0();                    // my stage(t) portion landed
        __builtin_amdgcn_s_barrier();// partner's too; all reads of t-1 done
        const __bf16* kb = (t & 1) ? kb1 : kb0;
        const __bf16* vb = (t & 1) ? vb1 : vb0;
        if (t < 17)                  // prefetch t+1 into the buffer read at t-1
            STAGE((long)(t + 1) * 64, (t & 1) ? kb0 : kb1, (t & 1) ? vb0 : vb1);
        bf16x8 kc0 = load_bf8(kb + (0 * 16 + r) * 32 + g * 8);
        bf16x8 kc1 = load_bf8(kb + (1 * 16 + r) * 32 + g * 8);
        bf16x8 kc2 = load_bf8(kb + (2 * 16 + r) * 32 + g * 8);
        bf16x8 kc3 = load_bf8(kb + (3 * 16 + r) * 32 + g * 8);
        bf16x4 vf[4][2];
        #pragma unroll
        for (int tt = 0; tt < 4; ++tt) {
            int pg = (((tt * 2 + (g >> 1)) ^ k2r) << 1) | (g & 1);
            #pragma unroll
            for (int dt = 0; dt < 2; ++dt)
                vf[tt][dt] = *reinterpret_cast<const bf16x4*>(
                    vb + (dt * 16 + r) * 64 + pg * 4);
        }
        f32x4 z = {};
        __builtin_amdgcn_s_setprio(1);
        f32x4 s0 = mfma32(kc0, qf, z);   // S^T: lane(g,r) q=r, m=tt*16+g*4+i
        f32x4 s1 = mfma32(kc1, qf, z);
        f32x4 s2 = mfma32(kc2, qf, z);
        f32x4 s3 = mfma32(kc3, qf, z);
        __builtin_amdgcn_s_setprio(0);
        bf16x4 pa0, pa1, pa2, pa3;
        #pragma unroll
        for (int i = 0; i < 4; ++i) pa0[i] = (__bf16)EXP2F(s0[i]);
        #pragma unroll
        for (int i = 0; i < 4; ++i) pa1[i] = (__bf16)EXP2F(s1[i]);
        #pragma unroll
        for (int i = 0; i < 4; ++i) pa2[i] = (__bf16)EXP2F(s2[i]);
        #pragma unroll
        for (int i = 0; i < 4; ++i) pa3[i] = (__bf16)EXP2F(s3[i]);
        __builtin_amdgcn_s_setprio(1);
        oa0 = mfma16(vf[0][0], pa0, oa0);
        oa1 = mfma16(vf[0][1], pa0, oa1);
        oal = mfma16(onesv,    pa0, oal);
        oa0 = mfma16(vf[1][0], pa1, oa0);
        oa1 = mfma16(vf[1][1], pa1, oa1);
        oal = mfma16(onesv,    pa1, oal);
        oa0 = mfma16(vf[2][0], pa2, oa0);
        oa1 = mfma16(vf[2][1], pa2, oa1);
        oal = mfma16(onesv,    pa2, oal);
        oa0 = mfma16(vf[3][0], pa3, oa0);
        oa1 = mfma16(vf[3][1], pa3, oa1);
        oal = mfma16(onesv,    pa3, oal);
        __builtin_amdgcn_s_setprio(0);
    }
    __builtin_amdgcn_s_barrier();
    float* F = reinterpret_cast<float*>(&sK[0][0][0]);   // 4096 f32 available
    *reinterpret_cast<f32x4*>(F + wave * 512 + r * 32 + g * 4) = oa0;
    *reinterpret_cast<f32x4*>(F + wave * 512 + r * 32 + 16 + g * 4) = oa1;
    if (g == 0) F[2048 + wave * 16 + r] = oal[0];
    __builtin_amdgcn_s_barrier();
    if (tid < 128) {
        int q = tid >> 2;            // 0..31
        int wpq = q >> 4, qq = q & 15;
        int d8 = (tid & 3) * 8;
        int base0 = wpq * 512 + qq * 32 + d8;
        int base1 = (wpq + 2) * 512 + qq * 32 + d8;
        f32x4 a0 = *reinterpret_cast<f32x4*>(F + base0) +
                   *reinterpret_cast<f32x4*>(F + base1);
        f32x4 a1 = *reinterpret_cast<f32x4*>(F + base0 + 4) +
                   *reinterpret_cast<f32x4*>(F + base1 + 4);
        float l = F[2048 + wpq * 16 + qq] + F[2048 + (wpq + 2) * 16 + qq];
        float inv = 1.0f / l;
        bf16x8 ov;
        #pragma unroll
        for (int i = 0; i < 4; ++i) {
            ov[i] = (__bf16)(a0[i] * inv);
            ov[4 + i] = (__bf16)(a1[i] * inv);
        }
        int b = bh >> 3, h = bh & 7;
        *reinterpret_cast<bf16x8*>(aoT + (long)(b * N + q0 + q) * C + h * 32 + d8) = ov;
    }
}

// ---------------- kernel 4: output projection + bias + residual ----------------
__global__ __launch_bounds__(256) void outp_kernel(const __bf16* __restrict__ Wb,
    const __bf16* __restrict__ aoT, const float* __restrict__ bo,
    const float* __restrict__ x, float* __restrict__ out) {
    int o0 = blockIdx.y * 64;
    int t0 = blockIdx.x * 16;
    int wave = threadIdx.x >> 6, lane = threadIdx.x & 63;
    int g = lane >> 4, r = lane & 15;
    int ow = o0 + wave * 16;
    const __bf16* W = Wb + 3 * 65536;   // Wo
    f32x4 acc = {};
    for (int k = 0; k < 8; ++k) {
        bf16x8 a = load_bf8(W + (ow + r) * C + k * 32 + g * 8);
        bf16x8 bfr = load_bf8(aoT + (long)(t0 + r) * C + k * 32 + g * 8);
        acc = mfma32(a, bfr, acc);
    }
    float bvw[4];
    #pragma unroll
    for (int i = 0; i < 4; ++i) bvw[i] = bo[ow + g * 4 + i];
    int t = t0 + r;
    int b = t / N, n = t % N;
    #pragma unroll
    for (int i = 0; i < 4; ++i) {
        long idx = ((long)b * C + ow + g * 4 + i) * N + n;
        out[idx] = acc[i] + bvw[i] + x[idx];
    }
}

extern "C" void kernel_launch(void* const* d_in, const int* in_sizes, int n_in,
                              void* d_out, int out_size, void* d_ws, size_t ws_size,
                              hipStream_t stream) {
    const float* x  = (const float*)d_in[0];
    const float* u  = (const float*)d_in[1];
    const float* Wq = (const float*)d_in[2];
    const float* bq = (const float*)d_in[3];
    const float* Wk = (const float*)d_in[4];
    const float* bk = (const float*)d_in[5];
    const float* Wv = (const float*)d_in[6];
    const float* bv = (const float*)d_in[7];
    const float* Wg = (const float*)d_in[8];
    const float* bg = (const float*)d_in[9];
    const float* Wo = (const float*)d_in[10];
    const float* bo = (const float*)d_in[11];
    float* out = (float*)d_out;

    char* ws = (char*)d_ws;
    size_t off = 0;
    auto alloc = [&](size_t bytes) {
        char* p = ws + off;
        off += (bytes + 255) & ~(size_t)255;
        return p;
    };
    __bf16* Wb  = (__bf16*)alloc((size_t)4 * 65536 * 2);
    __bf16* xT  = (__bf16*)alloc((size_t)T * C * 2);
    __bf16* gxT = (__bf16*)alloc((size_t)T * C * 2);
    __bf16* Qb  = (__bf16*)alloc((size_t)16 * N * 32 * 2);
    __bf16* Kb  = (__bf16*)alloc((size_t)16 * N * 32 * 2);
    __bf16* Vb  = (__bf16*)alloc((size_t)16 * N * 32 * 2);
    __bf16* aoT = (__bf16*)alloc((size_t)T * C * 2);

    wconv_kernel<<<256, 256, 0, stream>>>(Wq, Wk, Wv, Wo, Wb);
    prep_kernel<<<dim3(36, 8, 2), 256, 0, stream>>>(x, u, Wg, bg, xT, gxT);
    qkv_kernel<<<dim3(144, 4, 3), 256, 0, stream>>>(Wb, xT, gxT, bq, bk, bv, u, Qb, Kb, Vb);
    // MEASUREMENT ROUND: attn launched 5x (deterministic, identical output).
    // attn_dur = (total - 78.76) / 4. Reverts to 1x next round.
    attn_kernel<<<1152, 256, 0, stream>>>(Qb, Kb, Vb, aoT);
    attn_kernel<<<1152, 256, 0, stream>>>(Qb, Kb, Vb, aoT);
    attn_kernel<<<1152, 256, 0, stream>>>(Qb, Kb, Vb, aoT);
    attn_kernel<<<1152, 256, 0, stream>>>(Qb, Kb, Vb, aoT);
    attn_kernel<<<1152, 256, 0, stream>>>(Qb, Kb, Vb, aoT);
    outp_kernel<<<dim3(288, 4), 256, 0, stream>>>(Wb, aoT, bo, x, out);
}

// Round 11
// 78.256 us; speedup vs baseline: 2.5941x; 2.5941x over previous
//
#include <hip/hip_runtime.h>
#include <hip/hip_bf16.h>

typedef float f32x4 __attribute__((ext_vector_type(4)));
typedef __bf16 bf16x8 __attribute__((ext_vector_type(8)));
typedef __bf16 bf16x4 __attribute__((ext_vector_type(4)));
typedef short s16x4 __attribute__((ext_vector_type(4)));

constexpr int C = 256;
constexpr int N = 2304;           // 48*48 tokens per batch
constexpr int T = 2 * N;          // total tokens

#if __has_builtin(__builtin_amdgcn_exp2f)
#define EXP2F(x) __builtin_amdgcn_exp2f(x)
#else
#define EXP2F(x) exp2f(x)
#endif

__device__ __forceinline__ bf16x8 load_bf8(const __bf16* p) {
    return *reinterpret_cast<const bf16x8*>(p);
}

__device__ __forceinline__ f32x4 mfma32(bf16x8 a, bf16x8 b, f32x4 c) {
    return __builtin_amdgcn_mfma_f32_16x16x32_bf16(a, b, c, 0, 0, 0);
}

// K=16 MFMA: 4-element k-granules match the QK^T C/D output layout, so P feeds
// PV entirely in-register (no LDS redistribution). Verified correct R4-R10.
#if __has_builtin(__builtin_amdgcn_mfma_f32_16x16x16bf16_1k)
__device__ __forceinline__ f32x4 mfma16(bf16x4 a, bf16x4 b, f32x4 c) {
    return __builtin_amdgcn_mfma_f32_16x16x16bf16_1k(
        __builtin_bit_cast(s16x4, a), __builtin_bit_cast(s16x4, b), c, 0, 0, 0);
}
#else
__device__ __forceinline__ f32x4 mfma16(bf16x4 a, bf16x4 b, f32x4 c) {
    f32x4 d;
    asm volatile("v_mfma_f32_16x16x16_bf16 %0, %1, %2, %3"
                 : "=v"(d) : "v"(a), "v"(b), "v"(c));
    return d;
}
#endif

// async global->LDS, 16B per lane; dest = wave-uniform base + lane*16
__device__ __forceinline__ void gload_lds16(const __bf16* g, __bf16* l) {
    __builtin_amdgcn_global_load_lds(
        (const __attribute__((address_space(1))) void*)g,
        (__attribute__((address_space(3))) void*)l, 16, 0, 0);
}

#define VMCNT0() asm volatile("s_waitcnt vmcnt(0)" ::: "memory")
#define LGKM0()  asm volatile("s_waitcnt lgkmcnt(0)" ::: "memory")

// ---------------- kernel 0: convert Wq/Wk/Wv/Wo to bf16 ----------------
__global__ void wconv_kernel(const float* __restrict__ Wq, const float* __restrict__ Wk,
                             const float* __restrict__ Wv, const float* __restrict__ Wo,
                             __bf16* __restrict__ Wb) {
    const float* srcs[4] = {Wq, Wk, Wv, Wo};
    int m = blockIdx.x >> 6;
    int idx = (blockIdx.x & 63) * 256 + threadIdx.x;   // [0, 16384)
    float4 v = reinterpret_cast<const float4*>(srcs[m])[idx];
    bf16x4 o = { (__bf16)v.x, (__bf16)v.y, (__bf16)v.z, (__bf16)v.w };
    reinterpret_cast<bf16x4*>(Wb + m * 65536)[idx] = o;
}

// ---------------- kernel 1: gate + transpose (32-row tiles, 576 blocks) ----------------
__global__ void prep_kernel(const float* __restrict__ x, const float* __restrict__ u,
                            const float* __restrict__ Wg, const float* __restrict__ bg,
                            __bf16* __restrict__ xT, __bf16* __restrict__ gxT) {
    __shared__ float tile[32][65];
    int b = blockIdx.z, c0 = blockIdx.y * 32, n0 = blockIdx.x * 64;
    int t = threadIdx.x;
    const float* xp = x + (b * C + c0) * N + n0;
    #pragma unroll
    for (int r = 0; r < 8; ++r) {
        int cl = r * 4 + (t >> 6);
        int nl = t & 63;
        tile[cl][nl] = xp[cl * N + nl];
    }
    __syncthreads();
    int cq = (t & 7) * 4;
    #pragma unroll
    for (int it = 0; it < 2; ++it) {
        int nl = it * 32 + (t >> 3);
        float uv = u[b * N + n0 + nl];
        bf16x4 xo, go;
        #pragma unroll
        for (int j = 0; j < 4; ++j) {
            int c = c0 + cq + j;
            float xv = tile[cq + j][nl];
            float gate = 1.0f - (Wg[c] * uv + bg[c]);
            xo[j] = (__bf16)xv;
            go[j] = (__bf16)(xv * gate);
        }
        int tok = b * N + n0 + nl;
        *reinterpret_cast<bf16x4*>(xT + (long)tok * C + c0 + cq) = xo;
        *reinterpret_cast<bf16x4*>(gxT + (long)tok * C + c0 + cq) = go;
    }
}

// ---------------- kernel 2: QKV projections (bf16 MFMA) ----------------
// Q[bh][n][d], K[bh][m][d] (pre-scaled by SCALE*log2e*(1-u[m])), V[bh][d][n]
__global__ __launch_bounds__(256) void qkv_kernel(const __bf16* __restrict__ Wb,
    const __bf16* __restrict__ xT, const __bf16* __restrict__ gxT,
    const float* __restrict__ bq, const float* __restrict__ bk, const float* __restrict__ bv,
    const float* __restrict__ u,
    __bf16* __restrict__ Q, __bf16* __restrict__ K, __bf16* __restrict__ V) {
    int proj = blockIdx.z;            // 0=q,1=k,2=v
    int o0 = blockIdx.y * 64;
    int t0 = blockIdx.x * 32;
    int wave = threadIdx.x >> 6, lane = threadIdx.x & 63;
    int g = lane >> 4, r = lane & 15;
    int ow = o0 + wave * 16;
    const __bf16* W = Wb + proj * 65536;
    const __bf16* inp = (proj == 2) ? xT : gxT;
    f32x4 acc[2] = {};
    for (int k = 0; k < 8; ++k) {
        bf16x8 a = load_bf8(W + (ow + r) * C + k * 32 + g * 8);
        #pragma unroll
        for (int tb = 0; tb < 2; ++tb) {
            bf16x8 bfr = load_bf8(inp + (long)(t0 + tb * 16 + r) * C + k * 32 + g * 8);
            acc[tb] = mfma32(a, bfr, acc[tb]);
        }
    }
    const float* bias = (proj == 0) ? bq : (proj == 1) ? bk : bv;
    float bvw[4];
    #pragma unroll
    for (int i = 0; i < 4; ++i) bvw[i] = bias[ow + g * 4 + i];
    int h = ow >> 5, d0 = (ow & 31) + g * 4;
    const float SC = 0.17677669529663687f * 1.4426950408889634f;  // SCALE * log2(e)
    #pragma unroll
    for (int tb = 0; tb < 2; ++tb) {
        int t = t0 + tb * 16 + r;
        int b = t / N, n = t % N;
        if (proj == 2) {
            #pragma unroll
            for (int i = 0; i < 4; ++i)
                V[((long)(b * 8 + h) * 32 + d0 + i) * N + n] = (__bf16)(acc[tb][i] + bvw[i]);
        } else {
            bf16x4 outv;
            if (proj == 1) {
                float scale = SC * (1.0f - u[t]);
                #pragma unroll
                for (int i = 0; i < 4; ++i) outv[i] = (__bf16)((acc[tb][i] + bvw[i]) * scale);
            } else {
                #pragma unroll
                for (int i = 0; i < 4; ++i) outv[i] = (__bf16)(acc[tb][i] + bvw[i]);
            }
            __bf16* dst = (proj == 0) ? Q : K;
            *reinterpret_cast<bf16x4*>(dst + ((long)(b * 8 + h) * N + n) * 32 + d0) = outv;
        }
    }
}

// ---------------- kernel 3: flash attention (32-key tiles, 16KB LDS, 8 blk/CU) ----------------
// Measured R10: this kernel's predecessor = 31.1 us. Change: 32-key tiles halve
// LDS to 16KB -> target 8 blocks/CU (32 waves/CU, needs VGPR<=64). Unified T2
// slot-swizzle on K AND V: phys16Bslot = slot ^ ((row>>1)&7) (rows are 64B, so
// per 8-lane group all 8 bank-quads distinct; R9's K reads were 8-way aliased).
// Staging source pre-inverse-swizzled (involution: phys>>3 == logical>>3).
__global__ __launch_bounds__(256) void attn_kernel(const __bf16* __restrict__ Q,
    const __bf16* __restrict__ K, const __bf16* __restrict__ V,
    __bf16* __restrict__ aoT) {
    __shared__ __bf16 sMem[8192];       // 16KB: sK = [pair][buf][1024], sV after
    __bf16* sK = sMem;                  // pair*2048 + buf*1024
    __bf16* sV = sMem + 4096;
    int id = blockIdx.x;                // 1152 = 8 xcd * 144
    int xcd = id & 7, j = id >> 3;      // j in [0,144)
    int bh = xcd + 8 * (j / 72);
    int qblk = j % 72;
    int tid = threadIdx.x;
    int wave = tid >> 6, lane = tid & 63;
    int wp = wave & 1, pair = wave >> 1;
    int g = lane >> 4, r = lane & 15;
    int q0 = qblk * 32;
    const __bf16* Qg = Q + (long)bh * N * 32;
    const __bf16* Kg = K + (long)bh * N * 32 + (long)pair * 1152 * 32;
    const __bf16* Vg = V + (long)bh * 32 * N + pair * 1152;
    bf16x8 qf = load_bf8(Qg + (q0 + wp * 16 + r) * 32 + g * 8);   // B-frag Q^T
    // staging: phys slot s = wp*64+lane; logical l = s ^ ((s>>3)&7)
    int s_ = wp * 64 + lane;
    int l_ = s_ ^ ((s_ >> 3) & 7);
    const __bf16* kSrc = Kg + (l_ >> 2) * 32 + (l_ & 3) * 8;   // + m0*32
    const __bf16* vSrc = Vg + (long)(l_ >> 2) * N + (l_ & 3) * 8;  // + m0
    __bf16* kd0 = sK + pair * 2048;         // buf 0
    __bf16* vd0 = sV + pair * 2048;
    auto STAGE = [&](long m0, int buf) {
        gload_lds16(kSrc + m0 * 32, kd0 + buf * 1024 + wp * 512);
        gload_lds16(vSrc + m0,      vd0 + buf * 1024 + wp * 512);
    };
    // read offsets (lane-constant, elements)
    int key = (r >> 1) & 7;
    int pk0 = ((r * 4 + g) ^ key) * 8;                 // K row tt=0
    int pk1 = (((16 + r) * 4 + g) ^ key) * 8;          // K row tt=1
    int pv00 = (((r) * 4 + 0 + (g >> 1)) ^ key) * 8 + (g & 1) * 4;        // tt0 dt0
    int pv01 = (((16 + r) * 4 + 0 + (g >> 1)) ^ key) * 8 + (g & 1) * 4;   // tt0 dt1
    int pv10 = (((r) * 4 + 2 + (g >> 1)) ^ key) * 8 + (g & 1) * 4;        // tt1 dt0
    int pv11 = (((16 + r) * 4 + 2 + (g >> 1)) ^ key) * 8 + (g & 1) * 4;   // tt1 dt1
    bf16x4 onesv;
    #pragma unroll
    for (int i = 0; i < 4; ++i) onesv[i] = (__bf16)1.0f;
    f32x4 oa0 = {}, oa1 = {}, oal = {};
    STAGE(0, 0);
    for (int t = 0; t < 36; ++t) {
        LGKM0();                     // WAR: my reads of buf((t+1)&1) done
        VMCNT0();                    // my stage(t) landed
        __builtin_amdgcn_s_barrier();// partner's too
        const __bf16* kb = kd0 + (t & 1) * 1024;
        const __bf16* vb = vd0 + (t & 1) * 1024;
        if (t < 35) STAGE((long)(t + 1) * 32, (t & 1) ^ 1);
        // ---- LDS reads (swizzled) ----
        bf16x8 kc0 = load_bf8(kb + pk0);
        bf16x8 kc1 = load_bf8(kb + pk1);
        bf16x4 vf00 = *reinterpret_cast<const bf16x4*>(vb + pv00);
        bf16x4 vf01 = *reinterpret_cast<const bf16x4*>(vb + pv01);
        bf16x4 vf10 = *reinterpret_cast<const bf16x4*>(vb + pv10);
        bf16x4 vf11 = *reinterpret_cast<const bf16x4*>(vb + pv11);
        // ---- QK^T: S^T per lane(g,r): q=r, m = tt*16 + g*4 + i ----
        f32x4 z = {};
        __builtin_amdgcn_s_setprio(1);
        f32x4 s0 = mfma32(kc0, qf, z);
        f32x4 s1 = mfma32(kc1, qf, z);
        __builtin_amdgcn_s_setprio(0);
        // ---- exp2 + pack (scores pre-scaled by log2e) ----
        bf16x4 pa0, pa1;
        #pragma unroll
        for (int i = 0; i < 4; ++i) pa0[i] = (__bf16)EXP2F(s0[i]);
        #pragma unroll
        for (int i = 0; i < 4; ++i) pa1[i] = (__bf16)EXP2F(s1[i]);
        // ---- PV (K=16, in-register P) + denominator via ones-row ----
        __builtin_amdgcn_s_setprio(1);
        oa0 = mfma16(vf00, pa0, oa0);
        oa1 = mfma16(vf01, pa0, oa1);
        oal = mfma16(onesv, pa0, oal);
        oa0 = mfma16(vf10, pa1, oa0);
        oa1 = mfma16(vf11, pa1, oa1);
        oal = mfma16(onesv, pa1, oal);
        __builtin_amdgcn_s_setprio(0);
    }
    // combine the two key-halves via retired LDS (reads all drained pre-barrier)
    __builtin_amdgcn_s_barrier();
    float* F = reinterpret_cast<float*>(sMem);   // 4096 f32
    // lane(g,r): oa0[i]=O[d=g*4+i][q], oa1[i]=O[d=16+g*4+i][q], oal=denom(q)
    *reinterpret_cast<f32x4*>(F + wave * 512 + r * 32 + g * 4) = oa0;
    *reinterpret_cast<f32x4*>(F + wave * 512 + r * 32 + 16 + g * 4) = oa1;
    if (g == 0) F[2048 + wave * 16 + r] = oal[0];
    __builtin_amdgcn_s_barrier();
    if (tid < 128) {
        int q = tid >> 2;            // 0..31
        int wpq = q >> 4, qq = q & 15;
        int d8 = (tid & 3) * 8;
        int base0 = wpq * 512 + qq * 32 + d8;        // pair 0 (wave wpq)
        int base1 = (wpq + 2) * 512 + qq * 32 + d8;  // pair 1 (wave wpq+2)
        f32x4 a0 = *reinterpret_cast<f32x4*>(F + base0) +
                   *reinterpret_cast<f32x4*>(F + base1);
        f32x4 a1 = *reinterpret_cast<f32x4*>(F + base0 + 4) +
                   *reinterpret_cast<f32x4*>(F + base1 + 4);
        float l = F[2048 + wpq * 16 + qq] + F[2048 + (wpq + 2) * 16 + qq];
        float inv = 1.0f / l;
        bf16x8 ov;
        #pragma unroll
        for (int i = 0; i < 4; ++i) {
            ov[i] = (__bf16)(a0[i] * inv);
            ov[4 + i] = (__bf16)(a1[i] * inv);
        }
        int b = bh >> 3, h = bh & 7;
        *reinterpret_cast<bf16x8*>(aoT + (long)(b * N + q0 + q) * C + h * 32 + d8) = ov;
    }
}

// ---------------- kernel 4: output projection + bias + residual ----------------
__global__ __launch_bounds__(256) void outp_kernel(const __bf16* __restrict__ Wb,
    const __bf16* __restrict__ aoT, const float* __restrict__ bo,
    const float* __restrict__ x, float* __restrict__ out) {
    int o0 = blockIdx.y * 64;
    int t0 = blockIdx.x * 16;
    int wave = threadIdx.x >> 6, lane = threadIdx.x & 63;
    int g = lane >> 4, r = lane & 15;
    int ow = o0 + wave * 16;
    const __bf16* W = Wb + 3 * 65536;   // Wo
    f32x4 acc = {};
    for (int k = 0; k < 8; ++k) {
        bf16x8 a = load_bf8(W + (ow + r) * C + k * 32 + g * 8);
        bf16x8 bfr = load_bf8(aoT + (long)(t0 + r) * C + k * 32 + g * 8);
        acc = mfma32(a, bfr, acc);
    }
    float bvw[4];
    #pragma unroll
    for (int i = 0; i < 4; ++i) bvw[i] = bo[ow + g * 4 + i];
    int t = t0 + r;
    int b = t / N, n = t % N;
    #pragma unroll
    for (int i = 0; i < 4; ++i) {
        long idx = ((long)b * C + ow + g * 4 + i) * N + n;
        out[idx] = acc[i] + bvw[i] + x[idx];
    }
}

extern "C" void kernel_launch(void* const* d_in, const int* in_sizes, int n_in,
                              void* d_out, int out_size, void* d_ws, size_t ws_size,
                              hipStream_t stream) {
    const float* x  = (const float*)d_in[0];
    const float* u  = (const float*)d_in[1];
    const float* Wq = (const float*)d_in[2];
    const float* bq = (const float*)d_in[3];
    const float* Wk = (const float*)d_in[4];
    const float* bk = (const float*)d_in[5];
    const float* Wv = (const float*)d_in[6];
    const float* bv = (const float*)d_in[7];
    const float* Wg = (const float*)d_in[8];
    const float* bg = (const float*)d_in[9];
    const float* Wo = (const float*)d_in[10];
    const float* bo = (const float*)d_in[11];
    float* out = (float*)d_out;

    char* ws = (char*)d_ws;
    size_t off = 0;
    auto alloc = [&](size_t bytes) {
        char* p = ws + off;
        off += (bytes + 255) & ~(size_t)255;
        return p;
    };
    __bf16* Wb  = (__bf16*)alloc((size_t)4 * 65536 * 2);
    __bf16* xT  = (__bf16*)alloc((size_t)T * C * 2);
    __bf16* gxT = (__bf16*)alloc((size_t)T * C * 2);
    __bf16* Qb  = (__bf16*)alloc((size_t)16 * N * 32 * 2);
    __bf16* Kb  = (__bf16*)alloc((size_t)16 * N * 32 * 2);
    __bf16* Vb  = (__bf16*)alloc((size_t)16 * N * 32 * 2);
    __bf16* aoT = (__bf16*)alloc((size_t)T * C * 2);

    wconv_kernel<<<256, 256, 0, stream>>>(Wq, Wk, Wv, Wo, Wb);
    prep_kernel<<<dim3(36, 8, 2), 256, 0, stream>>>(x, u, Wg, bg, xT, gxT);
    qkv_kernel<<<dim3(144, 4, 3), 256, 0, stream>>>(Wb, xT, gxT, bq, bk, bv, u, Qb, Kb, Vb);
    attn_kernel<<<1152, 256, 0, stream>>>(Qb, Kb, Vb, aoT);
    outp_kernel<<<dim3(288, 4), 256, 0, stream>>>(Wb, aoT, bo, x, out);
}

// Round 12
// 77.732 us; speedup vs baseline: 2.6116x; 1.0067x over previous
//
#include <hip/hip_runtime.h>
#include <hip/hip_bf16.h>

typedef float f32x4 __attribute__((ext_vector_type(4)));
typedef __bf16 bf16x8 __attribute__((ext_vector_type(8)));
typedef __bf16 bf16x4 __attribute__((ext_vector_type(4)));
typedef short s16x4 __attribute__((ext_vector_type(4)));

constexpr int C = 256;
constexpr int N = 2304;           // 48*48 tokens per batch
constexpr int T = 2 * N;          // total tokens

#if __has_builtin(__builtin_amdgcn_exp2f)
#define EXP2F(x) __builtin_amdgcn_exp2f(x)
#else
#define EXP2F(x) exp2f(x)
#endif

__device__ __forceinline__ bf16x8 load_bf8(const __bf16* p) {
    return *reinterpret_cast<const bf16x8*>(p);
}

__device__ __forceinline__ f32x4 mfma32(bf16x8 a, bf16x8 b, f32x4 c) {
    return __builtin_amdgcn_mfma_f32_16x16x32_bf16(a, b, c, 0, 0, 0);
}

// K=16 MFMA: 4-element k-granules match the QK^T C/D output layout, so P feeds
// PV entirely in-register (no LDS redistribution). Verified correct R4-R11.
#if __has_builtin(__builtin_amdgcn_mfma_f32_16x16x16bf16_1k)
__device__ __forceinline__ f32x4 mfma16(bf16x4 a, bf16x4 b, f32x4 c) {
    return __builtin_amdgcn_mfma_f32_16x16x16bf16_1k(
        __builtin_bit_cast(s16x4, a), __builtin_bit_cast(s16x4, b), c, 0, 0, 0);
}
#else
__device__ __forceinline__ f32x4 mfma16(bf16x4 a, bf16x4 b, f32x4 c) {
    f32x4 d;
    asm volatile("v_mfma_f32_16x16x16_bf16 %0, %1, %2, %3"
                 : "=v"(d) : "v"(a), "v"(b), "v"(c));
    return d;
}
#endif

// async global->LDS, 16B per lane; dest = wave-uniform base + lane*16
__device__ __forceinline__ void gload_lds16(const __bf16* g, __bf16* l) {
    __builtin_amdgcn_global_load_lds(
        (const __attribute__((address_space(1))) void*)g,
        (__attribute__((address_space(3))) void*)l, 16, 0, 0);
}

#define VMCNT0() asm volatile("s_waitcnt vmcnt(0)" ::: "memory")

// ---------------- kernel 0: convert Wq/Wk/Wv/Wo to bf16 ----------------
__global__ void wconv_kernel(const float* __restrict__ Wq, const float* __restrict__ Wk,
                             const float* __restrict__ Wv, const float* __restrict__ Wo,
                             __bf16* __restrict__ Wb) {
    const float* srcs[4] = {Wq, Wk, Wv, Wo};
    int m = blockIdx.x >> 6;
    int idx = (blockIdx.x & 63) * 256 + threadIdx.x;   // [0, 16384)
    float4 v = reinterpret_cast<const float4*>(srcs[m])[idx];
    bf16x4 o = { (__bf16)v.x, (__bf16)v.y, (__bf16)v.z, (__bf16)v.w };
    reinterpret_cast<bf16x4*>(Wb + m * 65536)[idx] = o;
}

// ---------------- kernel 1: gate + transpose (32-row tiles, 576 blocks) ----------------
__global__ void prep_kernel(const float* __restrict__ x, const float* __restrict__ u,
                            const float* __restrict__ Wg, const float* __restrict__ bg,
                            __bf16* __restrict__ xT, __bf16* __restrict__ gxT) {
    __shared__ float tile[32][65];
    int b = blockIdx.z, c0 = blockIdx.y * 32, n0 = blockIdx.x * 64;
    int t = threadIdx.x;
    const float* xp = x + (b * C + c0) * N + n0;
    #pragma unroll
    for (int r = 0; r < 8; ++r) {
        int cl = r * 4 + (t >> 6);
        int nl = t & 63;
        tile[cl][nl] = xp[cl * N + nl];
    }
    __syncthreads();
    int cq = (t & 7) * 4;
    #pragma unroll
    for (int it = 0; it < 2; ++it) {
        int nl = it * 32 + (t >> 3);
        float uv = u[b * N + n0 + nl];
        bf16x4 xo, go;
        #pragma unroll
        for (int j = 0; j < 4; ++j) {
            int c = c0 + cq + j;
            float xv = tile[cq + j][nl];
            float gate = 1.0f - (Wg[c] * uv + bg[c]);
            xo[j] = (__bf16)xv;
            go[j] = (__bf16)(xv * gate);
        }
        int tok = b * N + n0 + nl;
        *reinterpret_cast<bf16x4*>(xT + (long)tok * C + c0 + cq) = xo;
        *reinterpret_cast<bf16x4*>(gxT + (long)tok * C + c0 + cq) = go;
    }
}

// ---------------- kernel 2: QKV projections (bf16 MFMA) ----------------
// Q[bh][n][d], K[bh][m][d] (pre-scaled by SCALE*log2e*(1-u[m])), V[bh][d][n]
__global__ __launch_bounds__(256) void qkv_kernel(const __bf16* __restrict__ Wb,
    const __bf16* __restrict__ xT, const __bf16* __restrict__ gxT,
    const float* __restrict__ bq, const float* __restrict__ bk, const float* __restrict__ bv,
    const float* __restrict__ u,
    __bf16* __restrict__ Q, __bf16* __restrict__ K, __bf16* __restrict__ V) {
    int proj = blockIdx.z;            // 0=q,1=k,2=v
    int o0 = blockIdx.y * 64;
    int t0 = blockIdx.x * 32;
    int wave = threadIdx.x >> 6, lane = threadIdx.x & 63;
    int g = lane >> 4, r = lane & 15;
    int ow = o0 + wave * 16;
    const __bf16* W = Wb + proj * 65536;
    const __bf16* inp = (proj == 2) ? xT : gxT;
    f32x4 acc[2] = {};
    for (int k = 0; k < 8; ++k) {
        bf16x8 a = load_bf8(W + (ow + r) * C + k * 32 + g * 8);
        #pragma unroll
        for (int tb = 0; tb < 2; ++tb) {
            bf16x8 bfr = load_bf8(inp + (long)(t0 + tb * 16 + r) * C + k * 32 + g * 8);
            acc[tb] = mfma32(a, bfr, acc[tb]);
        }
    }
    const float* bias = (proj == 0) ? bq : (proj == 1) ? bk : bv;
    float bvw[4];
    #pragma unroll
    for (int i = 0; i < 4; ++i) bvw[i] = bias[ow + g * 4 + i];
    int h = ow >> 5, d0 = (ow & 31) + g * 4;
    const float SC = 0.17677669529663687f * 1.4426950408889634f;  // SCALE * log2(e)
    #pragma unroll
    for (int tb = 0; tb < 2; ++tb) {
        int t = t0 + tb * 16 + r;
        int b = t / N, n = t % N;
        if (proj == 2) {
            #pragma unroll
            for (int i = 0; i < 4; ++i)
                V[((long)(b * 8 + h) * 32 + d0 + i) * N + n] = (__bf16)(acc[tb][i] + bvw[i]);
        } else {
            bf16x4 outv;
            if (proj == 1) {
                float scale = SC * (1.0f - u[t]);
                #pragma unroll
                for (int i = 0; i < 4; ++i) outv[i] = (__bf16)((acc[tb][i] + bvw[i]) * scale);
            } else {
                #pragma unroll
                for (int i = 0; i < 4; ++i) outv[i] = (__bf16)(acc[tb][i] + bvw[i]);
            }
            __bf16* dst = (proj == 0) ? Q : K;
            *reinterpret_cast<bf16x4*>(dst + ((long)(b * 8 + h) * N + n) * 32 + d0) = outv;
        }
    }
}

// ---------------- kernel 3: flash attention (free-running waves) ----------------
// Block = 4 waves x SAME 32 queries; key-split 4 (wave owns 576 keys, 18 iters
// of 32-key tiles). Each wave has a PRIVATE K/V LDS double-buffer (8KB) staged
// via global_load_lds -> NO barriers in the loop, per-wave vmcnt(0) with one-
// iteration prefetch cover. Each wave holds 2 Q-frags (32 q) so K/V fragment
// reads amortize 2x vs all prior rounds. Slot-swizzle (R11-verified):
// phys16Bslot = slot ^ ((slot>>3)&7), staging source pre-inverse-swizzled.
// In-register P (K=16 PV), denom via ones-MFMA. One combine at the end.
__global__ __launch_bounds__(256) void attn_kernel(const __bf16* __restrict__ Q,
    const __bf16* __restrict__ K, const __bf16* __restrict__ V,
    __bf16* __restrict__ aoT) {
    __shared__ __bf16 sMem[16384];      // 32KB: wave w owns [w*4096, w*4096+4096)
    int id = blockIdx.x;                // 1152 = 8 xcd * 144
    int xcd = id & 7, j = id >> 3;      // j in [0,144)
    int bh = xcd + 8 * (j / 72);
    int qblk = j % 72;
    int tid = threadIdx.x;
    int wave = tid >> 6, lane = tid & 63;
    int g = lane >> 4, r = lane & 15;
    int q0 = qblk * 32;
    const __bf16* Qg = Q + (long)bh * N * 32;
    const __bf16* Kg = K + (long)bh * N * 32 + (long)wave * 576 * 32;
    const __bf16* Vg = V + (long)bh * 32 * N + wave * 576;
    bf16x8 qf0 = load_bf8(Qg + (q0 + r) * 32 + g * 8);        // q = q0 + r
    bf16x8 qf1 = load_bf8(Qg + (q0 + 16 + r) * 32 + g * 8);   // q = q0 + 16 + r
    // staging: phys slot s = lane (inst0) / 64+lane (inst1); logical low bits
    // l0 = lane ^ ((lane>>3)&7); inst1 source = inst0 source + 16 rows.
    int l0 = lane ^ ((lane >> 3) & 7);
    const __bf16* kS = Kg + (l0 >> 2) * 32 + (l0 & 3) * 8;        // + m0*32
    const __bf16* vS = Vg + (long)(l0 >> 2) * N + (l0 & 3) * 8;   // + m0
    __bf16* kB = sMem + wave * 4096;        // K dbuf: 2 x 1024 elems
    __bf16* vB = kB + 2048;                 // V dbuf: 2 x 1024 elems
    auto STAGE = [&](long m0, int buf) {
        gload_lds16(kS + m0 * 32,       kB + buf * 1024);
        gload_lds16(kS + m0 * 32 + 512, kB + buf * 1024 + 512);
        gload_lds16(vS + m0,            vB + buf * 1024);
        gload_lds16(vS + 16 * N + m0,   vB + buf * 1024 + 512);
    };
    // read offsets (elements), R11-verified swizzle
    int key = (r >> 1) & 7;
    int pk0 = ((r * 4 + g) ^ key) * 8;
    int pk1 = (((16 + r) * 4 + g) ^ key) * 8;
    int pv00 = ((r * 4 + 0 + (g >> 1)) ^ key) * 8 + (g & 1) * 4;          // ks0 dt0
    int pv01 = (((16 + r) * 4 + 0 + (g >> 1)) ^ key) * 8 + (g & 1) * 4;   // ks0 dt1
    int pv10 = ((r * 4 + 2 + (g >> 1)) ^ key) * 8 + (g & 1) * 4;          // ks1 dt0
    int pv11 = (((16 + r) * 4 + 2 + (g >> 1)) ^ key) * 8 + (g & 1) * 4;   // ks1 dt1
    bf16x4 onesv;
    #pragma unroll
    for (int i = 0; i < 4; ++i) onesv[i] = (__bf16)1.0f;
    f32x4 oa00 = {}, oa01 = {}, oa10 = {}, oa11 = {};   // oa[qt][dt]
    f32x4 oal0 = {}, oal1 = {};                         // denom per q-tile
    STAGE(0, 0);
    for (int t = 0; t < 18; ++t) {
        VMCNT0();                    // K(t),V(t) landed (per-wave; no barrier)
        const __bf16* kb = kB + (t & 1) * 1024;
        const __bf16* vb = vB + (t & 1) * 1024;
        if (t < 17) STAGE((long)(t + 1) * 32, (t & 1) ^ 1);
        // ---- LDS reads (swizzled; private tile) ----
        bf16x8 kc0 = load_bf8(kb + pk0);
        bf16x8 kc1 = load_bf8(kb + pk1);
        bf16x4 vf00 = *reinterpret_cast<const bf16x4*>(vb + pv00);
        bf16x4 vf01 = *reinterpret_cast<const bf16x4*>(vb + pv01);
        bf16x4 vf10 = *reinterpret_cast<const bf16x4*>(vb + pv10);
        bf16x4 vf11 = *reinterpret_cast<const bf16x4*>(vb + pv11);
        // ---- QK^T for both q-frags (K frags amortized 2x) ----
        f32x4 z = {};
        __builtin_amdgcn_s_setprio(1);
        f32x4 s00 = mfma32(kc0, qf0, z);   // keys 0-15,  q = q0+r
        f32x4 s01 = mfma32(kc1, qf0, z);   // keys 16-31, q = q0+r
        f32x4 s10 = mfma32(kc0, qf1, z);   // keys 0-15,  q = q0+16+r
        f32x4 s11 = mfma32(kc1, qf1, z);
        __builtin_amdgcn_s_setprio(0);
        // ---- exp2 + pack (scores pre-scaled by log2e) ----
        bf16x4 pa00, pa01, pa10, pa11;
        #pragma unroll
        for (int i = 0; i < 4; ++i) pa00[i] = (__bf16)EXP2F(s00[i]);
        #pragma unroll
        for (int i = 0; i < 4; ++i) pa01[i] = (__bf16)EXP2F(s01[i]);
        #pragma unroll
        for (int i = 0; i < 4; ++i) pa10[i] = (__bf16)EXP2F(s10[i]);
        #pragma unroll
        for (int i = 0; i < 4; ++i) pa11[i] = (__bf16)EXP2F(s11[i]);
        // ---- PV (K=16, in-register P) + denominators (V frags amortized 2x) ----
        __builtin_amdgcn_s_setprio(1);
        oa00 = mfma16(vf00, pa00, oa00);
        oa01 = mfma16(vf01, pa00, oa01);
        oal0 = mfma16(onesv, pa00, oal0);
        oa00 = mfma16(vf10, pa01, oa00);
        oa01 = mfma16(vf11, pa01, oa01);
        oal0 = mfma16(onesv, pa01, oal0);
        oa10 = mfma16(vf00, pa10, oa10);
        oa11 = mfma16(vf01, pa10, oa11);
        oal1 = mfma16(onesv, pa10, oal1);
        oa10 = mfma16(vf10, pa11, oa10);
        oa11 = mfma16(vf11, pa11, oa11);
        oal1 = mfma16(onesv, pa11, oal1);
        __builtin_amdgcn_s_setprio(0);
    }
    // ---- combine 4 key-quarters (once per block) ----
    __syncthreads();
    float* F = reinterpret_cast<float*>(sMem);   // 4096 f32 partials + 128 denom
    float* D = F + 4096;
    // lane(g,r): oaXY[i] = O[d = Y*16+g*4+i][q = q0 + X*16 + r]
    *reinterpret_cast<f32x4*>(F + wave * 1024 + r * 32 + g * 4) = oa00;
    *reinterpret_cast<f32x4*>(F + wave * 1024 + r * 32 + 16 + g * 4) = oa01;
    *reinterpret_cast<f32x4*>(F + wave * 1024 + 512 + r * 32 + g * 4) = oa10;
    *reinterpret_cast<f32x4*>(F + wave * 1024 + 512 + r * 32 + 16 + g * 4) = oa11;
    if (g == 0) {
        D[wave * 32 + r] = oal0[0];
        D[wave * 32 + 16 + r] = oal1[0];
    }
    __syncthreads();
    {
        int q = tid >> 3;            // 0..31
        int d4 = (tid & 7) * 4;
        int qt = q >> 4, qq = q & 15;
        int base = qt * 512 + qq * 32 + d4;
        f32x4 sum = *reinterpret_cast<f32x4*>(F + base) +
                    *reinterpret_cast<f32x4*>(F + 1024 + base) +
                    *reinterpret_cast<f32x4*>(F + 2048 + base) +
                    *reinterpret_cast<f32x4*>(F + 3072 + base);
        float l = D[qt * 16 + qq] + D[32 + qt * 16 + qq] +
                  D[64 + qt * 16 + qq] + D[96 + qt * 16 + qq];
        float inv = 1.0f / l;
        bf16x4 ov;
        #pragma unroll
        for (int i = 0; i < 4; ++i) ov[i] = (__bf16)(sum[i] * inv);
        int b = bh >> 3, h = bh & 7;
        *reinterpret_cast<bf16x4*>(aoT + (long)(b * N + q0 + q) * C + h * 32 + d4) = ov;
    }
}

// ---------------- kernel 4: output projection + bias + residual ----------------
__global__ __launch_bounds__(256) void outp_kernel(const __bf16* __restrict__ Wb,
    const __bf16* __restrict__ aoT, const float* __restrict__ bo,
    const float* __restrict__ x, float* __restrict__ out) {
    int o0 = blockIdx.y * 64;
    int t0 = blockIdx.x * 16;
    int wave = threadIdx.x >> 6, lane = threadIdx.x & 63;
    int g = lane >> 4, r = lane & 15;
    int ow = o0 + wave * 16;
    const __bf16* W = Wb + 3 * 65536;   // Wo
    f32x4 acc = {};
    for (int k = 0; k < 8; ++k) {
        bf16x8 a = load_bf8(W + (ow + r) * C + k * 32 + g * 8);
        bf16x8 bfr = load_bf8(aoT + (long)(t0 + r) * C + k * 32 + g * 8);
        acc = mfma32(a, bfr, acc);
    }
    float bvw[4];
    #pragma unroll
    for (int i = 0; i < 4; ++i) bvw[i] = bo[ow + g * 4 + i];
    int t = t0 + r;
    int b = t / N, n = t % N;
    #pragma unroll
    for (int i = 0; i < 4; ++i) {
        long idx = ((long)b * C + ow + g * 4 + i) * N + n;
        out[idx] = acc[i] + bvw[i] + x[idx];
    }
}

extern "C" void kernel_launch(void* const* d_in, const int* in_sizes, int n_in,
                              void* d_out, int out_size, void* d_ws, size_t ws_size,
                              hipStream_t stream) {
    const float* x  = (const float*)d_in[0];
    const float* u  = (const float*)d_in[1];
    const float* Wq = (const float*)d_in[2];
    const float* bq = (const float*)d_in[3];
    const float* Wk = (const float*)d_in[4];
    const float* bk = (const float*)d_in[5];
    const float* Wv = (const float*)d_in[6];
    const float* bv = (const float*)d_in[7];
    const float* Wg = (const float*)d_in[8];
    const float* bg = (const float*)d_in[9];
    const float* Wo = (const float*)d_in[10];
    const float* bo = (const float*)d_in[11];
    float* out = (float*)d_out;

    char* ws = (char*)d_ws;
    size_t off = 0;
    auto alloc = [&](size_t bytes) {
        char* p = ws + off;
        off += (bytes + 255) & ~(size_t)255;
        return p;
    };
    __bf16* Wb  = (__bf16*)alloc((size_t)4 * 65536 * 2);
    __bf16* xT  = (__bf16*)alloc((size_t)T * C * 2);
    __bf16* gxT = (__bf16*)alloc((size_t)T * C * 2);
    __bf16* Qb  = (__bf16*)alloc((size_t)16 * N * 32 * 2);
    __bf16* Kb  = (__bf16*)alloc((size_t)16 * N * 32 * 2);
    __bf16* Vb  = (__bf16*)alloc((size_t)16 * N * 32 * 2);
    __bf16* aoT = (__bf16*)alloc((size_t)T * C * 2);

    wconv_kernel<<<256, 256, 0, stream>>>(Wq, Wk, Wv, Wo, Wb);
    prep_kernel<<<dim3(36, 8, 2), 256, 0, stream>>>(x, u, Wg, bg, xT, gxT);
    qkv_kernel<<<dim3(144, 4, 3), 256, 0, stream>>>(Wb, xT, gxT, bq, bk, bv, u, Qb, Kb, Vb);
    attn_kernel<<<1152, 256, 0, stream>>>(Qb, Kb, Vb, aoT);
    outp_kernel<<<dim3(288, 4), 256, 0, stream>>>(Wb, aoT, bo, x, out);
}